// Round 4
// baseline (411.317 us; speedup 1.0000x reference)
//
#include <hip/hip_runtime.h>

// ARNOLD_ENC: spike-latency encoding.
//   bin(b,n) = int(2.5*|trace[b,f]-center[c]| / 0.1 + 1); spike at t=bin iff bin<=99.
//   out: int32[100][1024][1024] = 400 MiB. Store-BW bound; ~66.3 us floor at fill's 6.33 TB/s.
//
// Measurement decomposition: per timed iter = d_ws poison 1600 MiB (~266 us, fixed) +
//   d_out poison 400 MiB (~66 us, fixed) + our kernel. Controllable region ~76 us as of R7.
// R1: t-strided 4KB bursts, regular stores    -> ~95 us kernels
// R2: contiguous stream, regular stores       -> ~92 us (pattern within block: neutral)
// R4: contiguous stream, nontemporal stores   -> ~89 us (NT: -3 us)
// R5: fused parked-window kernel, bins in reg -> ~85 us (whole 400 MiB hot at once: 4.9 TB/s)
// R6: bins pre-pass + 512-block linear sweep  -> ~79 us (5.5 TB/s; compact sweep helped)
// R7: fully fused, load-free store loop       -> ~76 us (5.6 TB/s; fill-identical instr stream)
// R8 (this): match fill's RESIDENT WAVE COUNT. Fill runs at 10% occupancy ~= 820 waves;
//   we ran 2048. Each wave is an independent 1KB-per-step stream at the memory controller;
//   2.5x more streams = more DRAM page churn per channel. Grid 256 blocks = 1024 waves;
//   each thread owns 4 rows (b0 + q*256), 16 bins in registers, 4 NT stores per t-plane
//   at quarter-plane offsets. Still zero loads in the loop; window = one plane, sweeping.

#define FF 128
#define TT 100
#define PLANE_GROUPS ((1024 * 1024) / 4)     // 262144 iv4 groups per t-plane (4 MiB)
#define QUARTER (PLANE_GROUPS / 4)           // 65536 groups = 256 rows
#define SWEEP_BLOCKS 256                     // 1024 waves ~= fill's residency

typedef int iv4 __attribute__((ext_vector_type(4)));   // native vector for nontemporal builtin

__global__ __launch_bounds__(256) void arnold_sweep_fused(
        const float* __restrict__ trace,
        const float* __restrict__ center,
        iv4* __restrict__ out) {
    const int b0  = blockIdx.x;      // 0..255: rows b0, b0+256, b0+512, b0+768
    const int tid = threadIdx.x;     // 0..255 = group-in-row (constant across iters)
    const int f   = tid >> 1;        // feature index (two threads per feature)
    const int c0  = (tid & 1) << 2;  // first of 4 consecutive centers

    float cc[4];
#pragma unroll
    for (int j = 0; j < 4; ++j) cc[j] = center[c0 + j];

    // 16 bins (4 rows x 4 centers) in registers. IEEE f32 (no fast-math): matches jnp
    // bit-exactly (same expression verified passing R1-R7). Values 1..101 or 255; t<=99
    // never matches 100/101/255, reproducing the reference mask.
    unsigned bins[4][4];
#pragma unroll
    for (int q = 0; q < 4; ++q) {
        const float x = trace[(b0 + q * 256) * FF + f];
#pragma unroll
        for (int j = 0; j < 4; ++j) {
            float tm = 2.5f * fabsf(x - cc[j]);
            bins[q][j] = (tm > 10.0f) ? 255u : (unsigned)(tm / 0.1f + 1.0f);
        }
    }

    // Pure store stream: per t-plane, 4 NT stores (one per owned row-quarter), then jump
    // one plane. No loads, no waitcnt. All indices compile-time static (no scratch).
    iv4* p = out + (unsigned)(b0 * 256 + tid);
#pragma unroll 2
    for (unsigned t = 0; t < TT; ++t) {
#pragma unroll
        for (int q = 0; q < 4; ++q) {
            iv4 v;
            v.x = (bins[q][0] == t) ? 1 : 0;
            v.y = (bins[q][1] == t) ? 1 : 0;
            v.z = (bins[q][2] == t) ? 1 : 0;
            v.w = (bins[q][3] == t) ? 1 : 0;
            __builtin_nontemporal_store(v, p + q * QUARTER);   // coalesced 1 KB/wave-instr
        }
        p += PLANE_GROUPS;
    }
}

extern "C" void kernel_launch(void* const* d_in, const int* in_sizes, int n_in,
                              void* d_out, int out_size, void* d_ws, size_t ws_size,
                              hipStream_t stream) {
    const float* trace  = (const float*)d_in[0];   // [1024,128] f32
    const float* center = (const float*)d_in[1];   // [8] f32
    iv4* out = (iv4*)d_out;                        // [100][1024][1024] int32
    (void)d_ws; (void)ws_size;                     // workspace not used

    arnold_sweep_fused<<<SWEEP_BLOCKS, 256, 0, stream>>>(trace, center, out);
}

// Round 5
// 407.137 us; speedup vs baseline: 1.0103x; 1.0103x over previous
//
#include <hip/hip_runtime.h>

// ARNOLD_ENC: spike-latency encoding.
//   bin(b,n) = int(2.5*|trace[b,f]-center[c]| / 0.1 + 1); spike at t=bin iff bin<=99.
//   out: int32[100][1024][1024] = 400 MiB. Store-BW bound; ~66.3 us floor at fill's 6.33 TB/s.
//
// Measurement decomposition: per timed iter = poison fills ~332 us (fixed) + our kernel.
// R1: t-strided 4KB bursts, regular stores    -> ~95 us kernels
// R2: contiguous stream, regular stores       -> ~92 us
// R4: contiguous stream, NT stores            -> ~89 us (NT helped WITH in-loop bins loads)
// R5: fused parked-window kernel, bins in reg -> ~85 us (whole 400 MiB hot: 4.9 TB/s)
// R6: bins pre-pass + 512-block linear sweep  -> ~79 us (5.5 TB/s)
// R7: fully fused, load-free store loop, NT   -> ~76 us (5.6 TB/s)  [best: 407.9 total]
// R8: 256 blocks, 4 rows/thread              -> ~79 us (WORSE; stream-count theory rejected)
// R9 (this): R7 verbatim but PLAIN stores. fillBufferAligned uses plain stores and hits
//   6.3 TB/s; NT bypasses L2's write-combining of full 128B lines + row-sequential burst
//   writeback. R4's "NT -3us" was measured with bins loads sharing vmcnt + an L2 window
//   worth protecting -- both confounds gone since R7. Last instruction-level difference
//   between our loop and fill's. If neutral/worse: NT was right, declare roofline.

#define FF 128
#define TT 100
#define PLANE_GROUPS ((1024 * 1024) / 4)     // 262144 iv4 groups per t-plane (4 MiB)
#define HALF_PLANE (PLANE_GROUPS / 2)        // 131072 = half-plane offset
#define SWEEP_BLOCKS 512                     // 512*256 threads cover exactly half a plane

typedef int iv4 __attribute__((ext_vector_type(4)));

__global__ __launch_bounds__(256) void arnold_sweep_fused(
        const float* __restrict__ trace,
        const float* __restrict__ center,
        iv4* __restrict__ out) {
    const int b0  = blockIdx.x;      // 0..511  (row b0; second row is b0+512)
    const int tid = threadIdx.x;     // 0..255  (= group-in-row; constant across iters)
    const int f   = tid >> 1;        // feature index (two threads per feature)
    const int c0  = (tid & 1) << 2;  // first of 4 consecutive centers

    float cc[4];
#pragma unroll
    for (int j = 0; j < 4; ++j) cc[j] = center[c0 + j];

    const float x0 = trace[b0 * FF + f];           // row b0
    const float x1 = trace[(b0 + 512) * FF + f];   // row b0+512

    // This thread's 8 bins, in registers. IEEE f32 (no fast-math): matches jnp bit-exactly
    // (same expression verified passing R1-R8). Values 1..101 or 255; t<=99 never matches
    // 100/101/255, reproducing the reference mask.
    unsigned bin0[4], bin1[4];
#pragma unroll
    for (int j = 0; j < 4; ++j) {
        float t0 = 2.5f * fabsf(x0 - cc[j]);
        bin0[j] = (t0 > 10.0f) ? 255u : (unsigned)(t0 / 0.1f + 1.0f);
        float t1 = 2.5f * fabsf(x1 - cc[j]);
        bin1[j] = (t1 > 10.0f) ? 255u : (unsigned)(t1 / 0.1f + 1.0f);
    }

    // Pure store stream: per t-plane, two 16B PLAIN stores (rows b0, b0+512), then jump
    // one plane. No loads, no waitcnt in the loop. L2 write-combines full lines and
    // bursts row-sequential writebacks (the fill path).
    iv4* p = out + (unsigned)(b0 * 256 + tid);
#pragma unroll 4
    for (unsigned t = 0; t < TT; ++t) {
        iv4 v0, v1;
        v0.x = (bin0[0] == t) ? 1 : 0;
        v0.y = (bin0[1] == t) ? 1 : 0;
        v0.z = (bin0[2] == t) ? 1 : 0;
        v0.w = (bin0[3] == t) ? 1 : 0;
        v1.x = (bin1[0] == t) ? 1 : 0;
        v1.y = (bin1[1] == t) ? 1 : 0;
        v1.z = (bin1[2] == t) ? 1 : 0;
        v1.w = (bin1[3] == t) ? 1 : 0;
        p[0] = v0;                   // coalesced 1 KB/wave-instr, L2 write-combined
        p[HALF_PLANE] = v1;
        p += PLANE_GROUPS;
    }
}

extern "C" void kernel_launch(void* const* d_in, const int* in_sizes, int n_in,
                              void* d_out, int out_size, void* d_ws, size_t ws_size,
                              hipStream_t stream) {
    const float* trace  = (const float*)d_in[0];   // [1024,128] f32
    const float* center = (const float*)d_in[1];   // [8] f32
    iv4* out = (iv4*)d_out;                        // [100][1024][1024] int32
    (void)d_ws; (void)ws_size;                     // workspace not used

    arnold_sweep_fused<<<SWEEP_BLOCKS, 256, 0, stream>>>(trace, center, out);
}